// Round 11
// baseline (93.988 us; speedup 1.0000x reference)
//
#include <hip/hip_runtime.h>

#define LL 64
#define NN 20
#define DTC 0.01f
#define NOISEC 1e-3f
#define LN2C 0.69314718056f

typedef __attribute__((ext_vector_type(8))) short short8x;
typedef __attribute__((ext_vector_type(4))) float f32x4;

// pack two floats to bf16x2 with round-to-nearest-even (manual, no HIP types)
__device__ __forceinline__ unsigned bf16r(float x) {
    union { float f; unsigned u; } a; a.f = x;
    return (a.u + (0x7fffu + ((a.u >> 16) & 1u))) >> 16;
}
__device__ __forceinline__ unsigned pk_bf16(float x, float y) {
    return bf16r(x) | (bf16r(y) << 16);
}

// One block (128 thr = 2 waves) per channel c = b*64+l; wave w owns
// d in [8w, 8w+8) of the block-Toeplitz sum and output half Mt=w.
// Block-Toeplitz MFMA (validated R8/R9): Qn[32I+i] = sum_d sum_k
// G_d[i][k]*Qsrc[32(I-d)+k], G_d[i][k] = g(32d+i-k), g = DT*q_n reversed,
// zero for negative arg. gt copy kk pos w holds r[w+kk] so A-reads are
// aligned ds_read_b128; Q zero-prefix handles the B boundary.
// Per step: each wave 16 MFMAs + 24 operand b128s; partial C for the
// non-owned Mt half shipped via pc[] (one f32x4); 2 barriers/step.
// fill_g split: wave w writes gt copies [4w, 4w+4).
__global__ __launch_bounds__(128, 2) void outage_kernel(
    const float* __restrict__ pathloss,
    const float* __restrict__ powers,
    float* __restrict__ out)
{
    __shared__ __align__(16) unsigned short gt[2][8][544];  // 8 shifted copies, ping-pong
    __shared__ __align__(16) unsigned short Qb[2][1024];    // [0,512)=zeros, [512,1024)=data
    __shared__ __align__(16) float pc[2][64][4];            // partial-C exchange

    const int tid  = threadIdx.x;
    const int wv   = tid >> 6;         // wave 0/1
    const int lane = tid & 63;
    const int c = blockIdx.x, b = c >> 6, l = c & 63;
    const int nh = lane & 15;          // MFMA m / n index
    const int qd = lane >> 4;          // MFMA quad (k-group)

    // ---- inline prep: rowsum + diag of pathloss row l (coalesced) ----
    const float pl = pathloss[l * LL + lane];
    float rs = pl;
    #pragma unroll
    for (int mk = 1; mk < 64; mk <<= 1) rs += __shfl_xor(rs, mk, 64);
    const float dg   = __shfl(pl, l, 64);
    const float dsum = rs - dg;

    // per-lane time constants for fill_g, tau = 8*lane + u
    float P2[8], P1[8];
    #pragma unroll
    for (int u = 0; u < 8; ++u) {
        P2[u] = exp2f((8 * lane + u) * DTC);
        P1[u] = P2[u] - 1.f;
    }

    // zero Q prefixes (both buffers) and gt tails [512,544) (both buffers)
    if (tid < 64) *((uint4*)&Qb[0][0] + tid)        = uint4{0u, 0u, 0u, 0u};
    else          *((uint4*)&Qb[1][0] + (tid - 64)) = uint4{0u, 0u, 0u, 0u};
    {
        const int buf = tid >> 6, k = (tid >> 3) & 7, w = tid & 7;
        *(uint2*)&gt[buf][k][512 + 4 * w] = uint2{0u, 0u};
    }

    // Q0(tau) = 1 - exp(-(2^{tau*DT}-1)*s0): 4 taus per thread
    const float p0 = powers[(b * NN + 0) * LL + l];
    const float s0 = dg * p0 / (p0 * dsum + NOISEC);
    float q7 = 0.f;
    {
        float v[4];
        #pragma unroll
        for (int u = 0; u < 4; ++u) {
            float t2 = exp2f((4 * tid + u) * DTC);
            v[u] = 1.f - expf(-(t2 - 1.f) * s0);
        }
        q7 = v[3];                                  // tid 127: Q0[511]
        *(uint2*)&Qb[0][512 + 4 * tid] = uint2{pk_bf16(v[0], v[1]), pk_bf16(v[2], v[3])};
    }

    const float p1v = powers[(b * NN + 1) * LL + l];
    float lossCh = (tid == 127) ? (1.f + p0 + (p1v + 1.f) * q7) : 0.f;

    // fill gt copies for one step; wave w writes copies [4w, 4w+4)
    auto fill_g = [&](int buf, float p) {
        float s  = dg * p / (p * dsum + NOISEC);
        float cm = s * LN2C * DTC;
        unsigned F[8];                               // F[0..3] own pairs, F[4..7] neighbor
        #pragma unroll
        for (int w = 0; w < 4; ++w) {
            float a  = expf(-P1[2 * w] * s) * P2[2 * w] * cm;
            float bb = expf(-P1[2 * w + 1] * s) * P2[2 * w + 1] * cm;
            F[w] = pk_bf16(a, bb);
        }
        #pragma unroll
        for (int w = 0; w < 4; ++w) {
            unsigned t = (unsigned)__shfl_down((int)F[w], 1, 64);
            F[4 + w] = (lane == 63) ? 0u : t;       // tau >= 512 -> 0
        }
        unsigned E[7];                               // odd-phase pairs
        #pragma unroll
        for (int j = 0; j < 7; ++j) E[j] = (F[j] >> 16) | (F[j + 1] << 16);
        if (wv == 0) {
            *(uint4*)&gt[buf][0][8 * lane] = uint4{F[0], F[1], F[2], F[3]};
            *(uint4*)&gt[buf][1][8 * lane] = uint4{E[0], E[1], E[2], E[3]};
            *(uint4*)&gt[buf][2][8 * lane] = uint4{F[1], F[2], F[3], F[4]};
            *(uint4*)&gt[buf][3][8 * lane] = uint4{E[1], E[2], E[3], E[4]};
        } else {
            *(uint4*)&gt[buf][4][8 * lane] = uint4{F[2], F[3], F[4], F[5]};
            *(uint4*)&gt[buf][5][8 * lane] = uint4{E[2], E[3], E[4], E[5]};
            *(uint4*)&gt[buf][6][8 * lane] = uint4{F[3], F[4], F[5], F[6]};
            *(uint4*)&gt[buf][7][8 * lane] = uint4{E[3], E[4], E[5], E[6]};
        }
    };
    fill_g(1, p1v);                                 // g-table for step n=1
    __syncthreads();

    const int kk    = (7 - nh) & 7;                 // this lane's copy index
    const int baseA = 511 - nh + 8 * qd - kk - 256 * wv;  // wave d-offset folded in
    const int baseB = 512 + 32 * nh + 8 * qd - 256 * wv;
    const int dstw  = 512 + 32 * nh + 4 * qd + 16 * wv;   // own Mt half

    float pnext = powers[(b * NN + 2) * LL + l];    // pw[n+1] entering n=1

    for (int n = 1; n < NN; ++n) {
        const unsigned short* psrc = &Qb[(n + 1) & 1][0];   // == (n-1)&1
        const unsigned short* pg   = &gt[n & 1][kk][0];
        unsigned short* pdst       = &Qb[n & 1][0];

        // operand reads for this wave's 8 d's (fenced by prior barrier)
        short8x Bv[8], A0v[8], A1v[8];
        #pragma unroll
        for (int d = 0; d < 8; ++d) Bv[d] = *(const short8x*)&psrc[baseB - 32 * d];
        #pragma unroll
        for (int d = 0; d < 8; ++d) {
            A0v[d] = *(const short8x*)&pg[baseA - 32 * d];
            A1v[d] = *(const short8x*)&pg[baseA - 32 * d - 16];
        }

        // g-table for step n+1 under the read/MFMA shadow (other gt buffer)
        float pfut = 0.f;
        if (n < NN - 1) {
            if (n <= NN - 3) pfut = powers[(b * NN + n + 2) * LL + l];
            fill_g((n + 1) & 1, pnext);
        }

        // 16 MFMAs: 4 independent chains (d even/odd x Mt)
        f32x4 a0a = {0.f,0.f,0.f,0.f}, a0b = {0.f,0.f,0.f,0.f};
        f32x4 a1a = {0.f,0.f,0.f,0.f}, a1b = {0.f,0.f,0.f,0.f};
        #pragma unroll
        for (int d = 0; d < 8; d += 2) {
            a0a = __builtin_amdgcn_mfma_f32_16x16x32_bf16(A0v[d],     Bv[d],     a0a, 0, 0, 0);
            a1a = __builtin_amdgcn_mfma_f32_16x16x32_bf16(A1v[d],     Bv[d],     a1a, 0, 0, 0);
            a0b = __builtin_amdgcn_mfma_f32_16x16x32_bf16(A0v[d + 1], Bv[d + 1], a0b, 0, 0, 0);
            a1b = __builtin_amdgcn_mfma_f32_16x16x32_bf16(A1v[d + 1], Bv[d + 1], a1b, 0, 0, 0);
        }
        f32x4 acc0 = a0a + a0b;     // partial Mt=0 (this wave's d-range)
        f32x4 acc1 = a1a + a1b;     // partial Mt=1

        // ship the non-owned Mt half, keep the owned one
        f32x4 ship = wv ? acc0 : acc1;
        f32x4 keep = wv ? acc1 : acc0;
        *(f32x4*)&pc[wv][lane][0] = ship;
        __syncthreads();            // barrier 1: partials + fill_g(n+1) visible

        f32x4 tot = keep + *(const f32x4*)&pc[1 - wv][lane][0];

        // write own Mt half of Qn (bf16)
        *(uint2*)&pdst[dstw] = uint2{pk_bf16(tot.x, tot.y), pk_bf16(tot.z, tot.w)};

        // loss tap: tid 127 (wave1 lane63, Mt1, col 15, row 31) = Qn[511]
        float wgt = (n < NN - 1) ? (pnext + 1.f) : 1.f;
        if (tid == 127) lossCh += wgt * tot.w;
        pnext = pfut;
        __syncthreads();            // barrier 2: Qn visible for next step
    }

    if (tid == 127) atomicAdd(out, lossCh);
}

extern "C" void kernel_launch(void* const* d_in, const int* in_sizes, int n_in,
                              void* d_out, int out_size, void* d_ws, size_t ws_size,
                              hipStream_t stream) {
    const float* pathloss = (const float*)d_in[0];
    const float* powers   = (const float*)d_in[1];
    float* outp = (float*)d_out;

    (void)hipMemsetAsync(d_out, 0, sizeof(float) * out_size, stream);
    outage_kernel<<<16 * LL, 128, 0, stream>>>(pathloss, powers, outp);
}

// Round 12
// 88.745 us; speedup vs baseline: 1.0591x; 1.0591x over previous
//
#include <hip/hip_runtime.h>

#define LL 64
#define NN 20
#define DTC 0.01f
#define NOISEC 1e-3f
#define LN2C 0.69314718056f

typedef __attribute__((ext_vector_type(8))) short short8x;
typedef __attribute__((ext_vector_type(4))) float f32x4;
typedef __attribute__((ext_vector_type(4))) int v4i;

// pack two floats to bf16x2 with round-to-nearest-even (manual, no HIP types)
__device__ __forceinline__ unsigned bf16r(float x) {
    union { float f; unsigned u; } a; a.f = x;
    return (a.u + (0x7fffu + ((a.u >> 16) & 1u))) >> 16;
}
__device__ __forceinline__ unsigned pk_bf16(float x, float y) {
    return bf16r(x) | (bf16r(y) << 16);
}

// B-fragment lane-shift: Bv[d+1](nh,qd) = Bv[d](nh-1,qd), 0 at nh==0.
// Exactly v_mov_dpp row_shr:1 (16-lane rows) with bound_ctrl zero-fill.
__device__ __forceinline__ short8x dpp_shr1(short8x v) {
    v4i p = __builtin_bit_cast(v4i, v);
    v4i q;
    q.x = __builtin_amdgcn_update_dpp(0, p.x, 0x111, 0xf, 0xf, true);
    q.y = __builtin_amdgcn_update_dpp(0, p.y, 0x111, 0xf, 0xf, true);
    q.z = __builtin_amdgcn_update_dpp(0, p.z, 0x111, 0xf, 0xf, true);
    q.w = __builtin_amdgcn_update_dpp(0, p.w, 0x111, 0xf, 0xf, true);
    return __builtin_bit_cast(short8x, q);
}

// One wave (64 thr) per channel c = b*64+l. NO barriers anywhere (per-wave
// in-order DS ordering carries all write->read deps).
// Block-Toeplitz MFMA (validated R8/R9): Qn[32I+i] = sum_d sum_k
// G_d[i][k]*Qsrc[32(I-d)+k], G_d[i][k] = g(32d+i-k), g = DT*q_n reversed,
// zero for negative arg. gt copy kk pos w holds r[w+kk] so every A-read is
// one aligned ds_read_b128; Q zero-prefix handles the B boundary.
// R12: B-fragments for d>=1 derived from Bv[0] via DPP row_shr:1 chains
// (VALU) instead of 15 ds_read_b128 — moves load off the contended LDS pipe.
__global__ __launch_bounds__(64, 1) void outage_kernel(
    const float* __restrict__ pathloss,
    const float* __restrict__ powers,
    float* __restrict__ out)
{
    __shared__ __align__(16) unsigned short gt[2][8][544];  // 8 shifted copies, ping-pong
    __shared__ __align__(16) unsigned short Qb[2][1024];    // [0,512)=zeros, [512,1024)=data

    const int lane = threadIdx.x;
    const int c = blockIdx.x, b = c >> 6, l = c & 63;
    const int nh = lane & 15;          // MFMA m / n index
    const int qd = lane >> 4;          // MFMA quad (k-group)

    // ---- inline prep: rowsum + diag of pathloss row l (coalesced) ----
    const float pl = pathloss[l * LL + lane];
    float rs = pl;
    #pragma unroll
    for (int mk = 1; mk < 64; mk <<= 1) rs += __shfl_xor(rs, mk, 64);
    const float dg   = __shfl(pl, l, 64);
    const float dsum = rs - dg;

    // per-lane time constants, tau = 8*lane + u
    float P2[8], P1[8];
    #pragma unroll
    for (int u = 0; u < 8; ++u) {
        P2[u] = exp2f((8 * lane + u) * DTC);
        P1[u] = P2[u] - 1.f;
    }

    // zero Q prefixes (1 KiB each) and gt tails [512,544) of both buffers
    *((uint4*)&Qb[0][0] + lane) = uint4{0u, 0u, 0u, 0u};
    *((uint4*)&Qb[1][0] + lane) = uint4{0u, 0u, 0u, 0u};
    {
        const int bb = lane >> 5, w = lane & 31;
        #pragma unroll
        for (int k = 0; k < 8; ++k) gt[bb][k][512 + w] = 0;
    }

    // Q0(tau) = 1 - exp(-(2^{tau*DT}-1)*s0), bf16 into Qb[0]
    const float p0 = powers[(b * NN + 0) * LL + l];
    const float s0 = dg * p0 / (p0 * dsum + NOISEC);
    float q7;
    {
        float v[8];
        #pragma unroll
        for (int u = 0; u < 8; ++u) v[u] = 1.f - expf(-P1[u] * s0);
        q7 = v[7];                                  // lane 63: Q0[511]
        uint4 d4 = { pk_bf16(v[0], v[1]), pk_bf16(v[2], v[3]),
                     pk_bf16(v[4], v[5]), pk_bf16(v[6], v[7]) };
        *(uint4*)&Qb[0][512 + 8 * lane] = d4;
    }

    const float p1v = powers[(b * NN + 1) * LL + l];
    float lossCh = 1.f + p0 + (p1v + 1.f) * q7;     // only lane 63's is used

    // fill the 8 shifted copies of r[tau] = DT*q_n(tau) for a step into buf
    auto fill_g = [&](int buf, float p) {
        float s  = dg * p / (p * dsum + NOISEC);
        float cm = s * LN2C * DTC;
        unsigned F[8];                               // F[0..3] own pairs, F[4..7] neighbor
        #pragma unroll
        for (int w = 0; w < 4; ++w) {
            float a  = expf(-P1[2 * w] * s) * P2[2 * w] * cm;
            float bb = expf(-P1[2 * w + 1] * s) * P2[2 * w + 1] * cm;
            F[w] = pk_bf16(a, bb);
        }
        #pragma unroll
        for (int w = 0; w < 4; ++w) {
            unsigned t = (unsigned)__shfl_down((int)F[w], 1, 64);
            F[4 + w] = (lane == 63) ? 0u : t;       // tau >= 512 -> 0
        }
        unsigned E[7];                               // odd-phase pairs
        #pragma unroll
        for (int j = 0; j < 7; ++j) E[j] = (F[j] >> 16) | (F[j + 1] << 16);
        #pragma unroll
        for (int k = 0; k < 8; ++k) {               // copy k pos 8L+w holds r[8L+w+k]
            uint4 d4;
            if ((k & 1) == 0) d4 = uint4{F[k / 2], F[k / 2 + 1], F[k / 2 + 2], F[k / 2 + 3]};
            else              d4 = uint4{E[k / 2], E[k / 2 + 1], E[k / 2 + 2], E[k / 2 + 3]};
            *(uint4*)&gt[buf][k][8 * lane] = d4;
        }
    };
    fill_g(1, p1v);                                 // g-table for step n=1

    const int kk    = (7 - nh) & 7;                 // this lane's copy index
    const int baseA = 511 - nh + 8 * qd - kk;       // == 0 mod 8 (16B aligned)
    const int baseB = 512 + 32 * nh + 8 * qd;
    const int dstw  = 512 + 32 * nh + 4 * qd;       // +16 for M-tile 1

    float pnext = powers[(b * NN + 2) * LL + l];    // pw[n+1] entering n=1

    for (int n = 1; n < NN; ++n) {
        const unsigned short* psrc = &Qb[(n + 1) & 1][0];   // == (n-1)&1
        const unsigned short* pg   = &gt[n & 1][kk][0];
        unsigned short* pdst       = &Qb[n & 1][0];

        // issue next-next power load early (lands during this step's work)
        float pfut = 0.f;
        if (n <= NN - 3) pfut = powers[(b * NN + n + 2) * LL + l];

        // ---- B: one ds_read_b128 (d=0) + DPP row_shr:1 chain for d>=1 ----
        short8x Bv[16];
        Bv[0] = *(const short8x*)&psrc[baseB];
        #pragma unroll
        for (int d = 1; d < 16; ++d) Bv[d] = dpp_shr1(Bv[d - 1]);

        // ---- A operands for this step (32 x ds_read_b128) ----
        short8x A0v[16], A1v[16];
        #pragma unroll
        for (int d = 0; d < 16; ++d) {
            A0v[d] = *(const short8x*)&pg[baseA - 32 * d];
            A1v[d] = *(const short8x*)&pg[baseA - 32 * d - 16];
        }

        // ---- fill g-table for step n+1 (independent buffer) under the
        //      MFMA shadow; uses pnext loaded one iteration ago ----
        if (n < NN - 1) fill_g((n + 1) & 1, pnext);

        // ---- 4 independent MFMA chains (d even/odd x 2 M-tiles) ----
        f32x4 acc0a = {0.f, 0.f, 0.f, 0.f}, acc0b = {0.f, 0.f, 0.f, 0.f};
        f32x4 acc1a = {0.f, 0.f, 0.f, 0.f}, acc1b = {0.f, 0.f, 0.f, 0.f};
        #pragma unroll
        for (int d = 0; d < 16; d += 2) {
            acc0a = __builtin_amdgcn_mfma_f32_16x16x32_bf16(A0v[d],     Bv[d],     acc0a, 0, 0, 0);
            acc1a = __builtin_amdgcn_mfma_f32_16x16x32_bf16(A1v[d],     Bv[d],     acc1a, 0, 0, 0);
            acc0b = __builtin_amdgcn_mfma_f32_16x16x32_bf16(A0v[d + 1], Bv[d + 1], acc0b, 0, 0, 0);
            acc1b = __builtin_amdgcn_mfma_f32_16x16x32_bf16(A1v[d + 1], Bv[d + 1], acc1b, 0, 0, 0);
        }
        f32x4 acc0 = acc0a + acc0b;
        f32x4 acc1 = acc1a + acc1b;

        // write Qn (bf16): lane holds rows 4qd..4qd+3 of both M-tiles, col nh
        *(uint2*)&pdst[dstw]      = uint2{pk_bf16(acc0.x, acc0.y), pk_bf16(acc0.z, acc0.w)};
        *(uint2*)&pdst[dstw + 16] = uint2{pk_bf16(acc1.x, acc1.y), pk_bf16(acc1.z, acc1.w)};

        // loss tap: lane 63 acc1.w == Qn[511] (row 31, col 15), fp32 precision
        float wgt = (n < NN - 1) ? (pnext + 1.f) : 1.f;   // pnext == pw[n+1]
        lossCh += wgt * acc1.w;
        pnext = pfut;
    }

    if (lane == 63) atomicAdd(out, lossCh);
}

extern "C" void kernel_launch(void* const* d_in, const int* in_sizes, int n_in,
                              void* d_out, int out_size, void* d_ws, size_t ws_size,
                              hipStream_t stream) {
    const float* pathloss = (const float*)d_in[0];
    const float* powers   = (const float*)d_in[1];
    float* outp = (float*)d_out;

    (void)hipMemsetAsync(d_out, 0, sizeof(float) * out_size, stream);
    outage_kernel<<<16 * LL, 64, 0, stream>>>(pathloss, powers, outp);
}